// Round 3
// baseline (592.243 us; speedup 1.0000x reference)
//
#include <hip/hip_runtime.h>
#include <hip/hip_bf16.h>

// SelfAttentionHead: B=4, S=4096, D=256, fp32 in/out.
// out = qp + softmax(tril_mul(qp kp^T / 16)) @ vp, masked entries enter softmax as 0.
// R3: barrier-free single-wave flash attention, K/V read direct from L2 (no LDS staging).
// Split-K 2-way; combine merges halves + masked-zero correction (Z += (S-1-q)e^{-M},
// num += e^{-M} SuffV[q]) + qp residual.

typedef __bf16 bf16x8 __attribute__((ext_vector_type(8)));
typedef float f32x4 __attribute__((ext_vector_type(4)));

__device__ __forceinline__ unsigned short f2bf_u(float f) {
  unsigned u = __float_as_uint(f);
  u += 0x7fffu + ((u >> 16) & 1u);
  return (unsigned short)(u >> 16);
}

// ---------------- WT[j][k] = bf16(W[k][j]) ----------------
__global__ __launch_bounds__(256) void wt_kernel(
    const float* __restrict__ Wq, const float* __restrict__ Wk, const float* __restrict__ Wv,
    unsigned short* __restrict__ WTq, unsigned short* __restrict__ WTk, unsigned short* __restrict__ WTv) {
  int j = blockIdx.x & 255;
  int wsel = blockIdx.x >> 8;
  const float* W = wsel == 0 ? Wq : (wsel == 1 ? Wk : Wv);
  unsigned short* WT = wsel == 0 ? WTq : (wsel == 1 ? WTk : WTv);
  int k = threadIdx.x;
  WT[j * 256 + k] = f2bf_u(W[k * 256 + j]);
}

// ---------------- Fused projection GEMMs: one launch, grid (256, 3) ----------------
__global__ __launch_bounds__(256) void proj_all_kernel(
    const float* __restrict__ q_in, const float* __restrict__ k_in, const float* __restrict__ v_in,
    const unsigned short* __restrict__ WTq, const unsigned short* __restrict__ WTk,
    const unsigned short* __restrict__ WTv,
    const float* __restrict__ bq, const float* __restrict__ bk, const float* __restrict__ bv,
    float* __restrict__ qpf, unsigned short* __restrict__ qpb,
    unsigned short* __restrict__ kpb,
    float* __restrict__ vpf, unsigned short* __restrict__ vptb) {
  int mode = blockIdx.y;
  const float* X = mode == 0 ? q_in : (mode == 1 ? k_in : v_in);
  const unsigned short* WT = mode == 0 ? WTq : (mode == 1 ? WTk : WTv);
  const float* bias = mode == 0 ? bq : (mode == 1 ? bk : bv);

  int rt = blockIdx.x;
  int tid = threadIdx.x;
  int w = tid >> 6, l = tid & 63, g = l >> 4, lm = l & 15;
  int arow = rt * 64 + w * 16 + lm;

  f32x4 acc[16];
#pragma unroll
  for (int i = 0; i < 16; i++) acc[i] = (f32x4){0.f, 0.f, 0.f, 0.f};

#pragma unroll
  for (int kb = 0; kb < 256; kb += 32) {
    const float* ap = X + arow * 256 + kb + 8 * g;
    float4 a0 = *(const float4*)ap;
    float4 a1 = *(const float4*)(ap + 4);
    bf16x8 af;
    af[0] = (__bf16)a0.x; af[1] = (__bf16)a0.y; af[2] = (__bf16)a0.z; af[3] = (__bf16)a0.w;
    af[4] = (__bf16)a1.x; af[5] = (__bf16)a1.y; af[6] = (__bf16)a1.z; af[7] = (__bf16)a1.w;
#pragma unroll
    for (int nt = 0; nt < 16; nt++) {
      bf16x8 bf = *(const bf16x8*)(WT + (nt * 16 + lm) * 256 + kb + 8 * g);
      acc[nt] = __builtin_amdgcn_mfma_f32_16x16x32_bf16(af, bf, acc[nt], 0, 0, 0);
    }
  }

#pragma unroll
  for (int nt = 0; nt < 16; nt++) {
    int col = nt * 16 + lm;
    float bb = bias[col];
#pragma unroll
    for (int r = 0; r < 4; r++) {
      int orow = rt * 64 + w * 16 + 4 * g + r;
      float v = acc[nt][r] + bb;
      int idx = orow * 256 + col;
      if (mode == 0) {
        qpf[idx] = v;
        qpb[idx] = f2bf_u(v * 0.0625f);  // fold 1/sqrt(D)=1/16 into Q
      } else if (mode == 1) {
        kpb[idx] = f2bf_u(v);
      } else {
        vpf[idx] = v;
        int b = orow >> 12, s = orow & 4095;
        vptb[(b * 256 + col) * 4096 + s] = f2bf_u(v);  // vpT[b][d][s]
      }
    }
  }
}

// ---------------- Suffix-sum of vp (exclusive), 64-row chunks ----------------
__global__ __launch_bounds__(256) void scan1(const float* __restrict__ vpf, float* __restrict__ ctot) {
  int c = blockIdx.x, b = blockIdx.y, d = threadIdx.x;
  const float* base = vpf + (b * 4096 + c * 64) * 256 + d;
  float acc = 0.f;
#pragma unroll 4
  for (int r = 0; r < 64; r++) acc += base[r * 256];
  ctot[(b * 64 + c) * 256 + d] = acc;
}

__global__ __launch_bounds__(256) void scan2(const float* __restrict__ vpf, const float* __restrict__ ctot,
                                             float* __restrict__ suffv) {
  int c = blockIdx.x, b = blockIdx.y, d = threadIdx.x;
  float acc = 0.f;
  for (int c2 = c + 1; c2 < 64; c2++) acc += ctot[(b * 64 + c2) * 256 + d];
  const float* base = vpf + (b * 4096 + c * 64) * 256 + d;
  float* sbase = suffv + (b * 4096 + c * 64) * 256 + d;
  for (int r = 63; r >= 0; r--) {
    sbase[r * 256] = acc;
    acc += base[r * 256];
  }
}

// ---------------- Barrier-free single-wave flash attention ----------------
// 2048 blocks x 64 threads. bid&7 -> (b = (bid&7)>>1, s = bid&1): XCD round-robin pins one
// batch per XCD (K+V bf16 = 4MB fits 4MB L2). t = bitrev8(bid>>3): 16-row q-tile, uniform
// work mix per CU. s splits the causal k-range [0, t/4+1) into halves; s=1 gets diagonal.
// K and V fragments are read directly from global (L2-hit), P round-trips via 2.3KB LDS.
__global__ __launch_bounds__(64, 2) void attn3_kernel(
    const unsigned short* __restrict__ qpb, const unsigned short* __restrict__ kpb,
    const unsigned short* __restrict__ vptb,
    float* __restrict__ O0, float* __restrict__ O1, float* __restrict__ mzbuf) {
  __shared__ unsigned short Plds[16][72];

  int bid = blockIdx.x;
  int low = bid & 7;
  int b = low >> 1, s = low & 1;
  int t = (int)(__brev((unsigned)(bid >> 3)) >> 24);

  int nk = (t >> 2) + 1;
  int half = nk >> 1;
  int k0 = s ? half : 0;
  int k1 = s ? nk : half;

  int l = threadIdx.x, g = l >> 4, lm = l & 15;

  // Q fragments: rows t*16 + lm, pre-scaled by 1/16
  bf16x8 qa[8];
  const unsigned short* qb0 = qpb + (b * 4096 + t * 16 + lm) * 256 + 8 * g;
#pragma unroll
  for (int d0 = 0; d0 < 8; d0++) qa[d0] = *(const bf16x8*)(qb0 + d0 * 32);

  float m_[4], Z_[4];
  f32x4 O[16];
#pragma unroll
  for (int r = 0; r < 4; r++) { m_[r] = -1e30f; Z_[r] = 0.f; }
#pragma unroll
  for (int i = 0; i < 16; i++) O[i] = (f32x4){0.f, 0.f, 0.f, 0.f};

  const unsigned short* kb_base = kpb + (size_t)(b * 4096) * 256 + lm * 256 + 8 * g;
  const unsigned short* vb_base = vptb + (size_t)(b * 256) * 4096 + lm * 4096 + 8 * g;

  for (int kt = k0; kt < k1; kt++) {
    // ---- QK^T: 16 q-rows x 64 k-cols, K fragments straight from L2 ----
    f32x4 sc_[4];
#pragma unroll
    for (int jt = 0; jt < 4; jt++) sc_[jt] = (f32x4){0.f, 0.f, 0.f, 0.f};
    const unsigned short* kf_base = kb_base + kt * 64 * 256;
#pragma unroll
    for (int d0 = 0; d0 < 8; d0++) {
#pragma unroll
      for (int jt = 0; jt < 4; jt++) {
        bf16x8 kf = *(const bf16x8*)(kf_base + jt * 16 * 256 + d0 * 32);
        sc_[jt] = __builtin_amdgcn_mfma_f32_16x16x32_bf16(qa[d0], kf, sc_[jt], 0, 0, 0);
      }
    }

    if (kt == nk - 1) {  // diagonal tile (only s==1 reaches it): strict upper -> -inf
      int lim = (t & 3) * 16 + 4 * g;
#pragma unroll
      for (int jt = 0; jt < 4; jt++)
#pragma unroll
        for (int r = 0; r < 4; r++)
          if (jt * 16 + lm > lim + r) sc_[jt][r] = -1e30f;
    }

    // ---- online softmax: rows 4g+r, reduce across the 16 lanes of group g ----
    float mx[4], mn[4], scl[4], rs[4];
#pragma unroll
    for (int r = 0; r < 4; r++)
      mx[r] = fmaxf(fmaxf(sc_[0][r], sc_[1][r]), fmaxf(sc_[2][r], sc_[3][r]));
#pragma unroll
    for (int off = 1; off < 16; off <<= 1)
#pragma unroll
      for (int r = 0; r < 4; r++) mx[r] = fmaxf(mx[r], __shfl_xor(mx[r], off, 16));
#pragma unroll
    for (int r = 0; r < 4; r++) {
      mn[r] = fmaxf(m_[r], mx[r]);
      scl[r] = __expf(m_[r] - mn[r]);
      m_[r] = mn[r];
      rs[r] = 0.f;
    }
#pragma unroll
    for (int jt = 0; jt < 4; jt++)
#pragma unroll
      for (int r = 0; r < 4; r++) {
        float p = __expf(sc_[jt][r] - mn[r]);
        rs[r] += p;
        Plds[4 * g + r][jt * 16 + lm] = f2bf_u(p);
      }
#pragma unroll
    for (int off = 1; off < 16; off <<= 1)
#pragma unroll
      for (int r = 0; r < 4; r++) rs[r] += __shfl_xor(rs[r], off, 16);
#pragma unroll
    for (int r = 0; r < 4; r++) Z_[r] = Z_[r] * scl[r] + rs[r];
#pragma unroll
    for (int dt = 0; dt < 16; dt++)
#pragma unroll
      for (int r = 0; r < 4; r++) O[dt][r] *= scl[r];

    // P read-back (same wave; lgkmcnt ordering, no barrier)
    bf16x8 pa0 = *(const bf16x8*)&Plds[lm][8 * g];
    bf16x8 pa1 = *(const bf16x8*)&Plds[lm][32 + 8 * g];

    // ---- PV: O[16x256] += P[16x64] @ V[64x256], V fragments straight from L2 ----
    const unsigned short* vf_base = vb_base + kt * 64;
#pragma unroll
    for (int dt = 0; dt < 16; dt++) {
      bf16x8 vf0 = *(const bf16x8*)(vf_base + dt * 16 * 4096);
      bf16x8 vf1 = *(const bf16x8*)(vf_base + dt * 16 * 4096 + 32);
      O[dt] = __builtin_amdgcn_mfma_f32_16x16x32_bf16(pa0, vf0, O[dt], 0, 0, 0);
      O[dt] = __builtin_amdgcn_mfma_f32_16x16x32_bf16(pa1, vf1, O[dt], 0, 0, 0);
    }
  }

  // ---- write partial O, m, Z ----
  float* Op = s ? O1 : O0;
#pragma unroll
  for (int r = 0; r < 4; r++) {
    int grow = b * 4096 + t * 16 + 4 * g + r;
#pragma unroll
    for (int dt = 0; dt < 16; dt++)
      Op[grow * 256 + dt * 16 + lm] = O[dt][r];
    if (lm == 0) {
      mzbuf[s * 16384 + grow] = m_[r];
      mzbuf[32768 + s * 16384 + grow] = Z_[r];
    }
  }
}

// ---------------- combine: merge halves + masked-zero correction + qp add ----------------
__global__ __launch_bounds__(256) void combine_kernel(
    const float* __restrict__ O0, const float* __restrict__ O1, const float* __restrict__ mzbuf,
    const float* __restrict__ qpf, const float* __restrict__ suffv, float* __restrict__ out) {
  int grow = blockIdx.x * 4 + (threadIdx.x >> 6);
  int col = (threadIdx.x & 63) * 4;
  float m0 = mzbuf[grow], m1 = mzbuf[16384 + grow];
  float Z0 = mzbuf[32768 + grow], Z1 = mzbuf[32768 + 16384 + grow];
  float M = fmaxf(m0, m1);
  float f0 = __expf(m0 - M), f1 = __expf(m1 - M);
  float Zm = Z0 * f0 + Z1 * f1;
  int q = grow & 4095;
  int nmask = 4095 - q;
  float scl, e0, Zf;
  if (nmask > 0) {
    float Mf = fmaxf(M, 0.f);
    scl = __expf(M - Mf);
    e0 = __expf(-Mf);
    Zf = Zm * scl + (float)nmask * e0;
  } else {
    scl = 1.f; e0 = 0.f; Zf = Zm;
  }
  float rZ = 1.f / Zf;
  float a0 = f0 * scl * rZ, a1 = f1 * scl * rZ, a2 = e0 * rZ;
  int base = grow * 256 + col;
  float4 o0 = *(const float4*)&O0[base];
  float4 o1 = *(const float4*)&O1[base];
  float4 qp = *(const float4*)&qpf[base];
  float4 sv = *(const float4*)&suffv[base];
  float4 res;
  res.x = qp.x + o0.x * a0 + o1.x * a1 + sv.x * a2;
  res.y = qp.y + o0.y * a0 + o1.y * a1 + sv.y * a2;
  res.z = qp.z + o0.z * a0 + o1.z * a1 + sv.z * a2;
  res.w = qp.w + o0.w * a0 + o1.w * a1 + sv.w * a2;
  *(float4*)&out[base] = res;
}

// ---------------- launch ----------------
extern "C" void kernel_launch(void* const* d_in, const int* in_sizes, int n_in,
                              void* d_out, int out_size, void* d_ws, size_t ws_size,
                              hipStream_t stream) {
  const float* v_in = (const float*)d_in[0];
  const float* k_in = (const float*)d_in[1];
  const float* q_in = (const float*)d_in[2];
  const float* Wq = (const float*)d_in[3];
  const float* bq = (const float*)d_in[4];
  const float* Wk = (const float*)d_in[5];
  const float* bk = (const float*)d_in[6];
  const float* Wv = (const float*)d_in[7];
  const float* bv = (const float*)d_in[8];
  float* out = (float*)d_out;

  char* p = (char*)d_ws;
  float* qpf = (float*)(p + 0);                            // 16 MB
  float* vpf = (float*)(p + 16777216);                     // 16 MB (reused as O1)
  float* suffv = (float*)(p + 33554432);                   // 16 MB
  unsigned short* qpb = (unsigned short*)(p + 50331648);   // 8 MB (scaled 1/16)
  unsigned short* kpb = (unsigned short*)(p + 58720256);   // 8 MB
  unsigned short* vptb = (unsigned short*)(p + 67108864);  // 8 MB, [B][D][S]
  unsigned short* WTq = (unsigned short*)(p + 75497472);   // 128 KB
  unsigned short* WTk = (unsigned short*)(p + 75628544);   // 128 KB
  unsigned short* WTv = (unsigned short*)(p + 75759616);   // 128 KB
  float* mzbuf = (float*)(p + 75497472);                   // 256 KB, reuses WTq+WTk (dead after proj)
  float* ctot = (float*)(p + 75759616);                    // 256 KB, reuses WTv+tail (dead after proj)
  float* O1 = vpf;                                         // vpf dead after scan2
  float* O0 = out;                                         // d_out doubles as s=0 partial

  wt_kernel<<<768, 256, 0, stream>>>(Wq, Wk, Wv, WTq, WTk, WTv);
  proj_all_kernel<<<dim3(256, 3), 256, 0, stream>>>(q_in, k_in, v_in, WTq, WTk, WTv,
                                                    bq, bk, bv, qpf, qpb, kpb, vpf, vptb);
  scan1<<<dim3(64, 4), 256, 0, stream>>>(vpf, ctot);
  scan2<<<dim3(64, 4), 256, 0, stream>>>(vpf, ctot, suffv);
  attn3_kernel<<<2048, 64, 0, stream>>>(qpb, kpb, vptb, O0, O1, mzbuf);
  combine_kernel<<<4096, 256, 0, stream>>>(O0, O1, mzbuf, qpf, suffv, out);
}

// Round 4
// 198.444 us; speedup vs baseline: 2.9844x; 2.9844x over previous
//
#include <hip/hip_runtime.h>
#include <hip/hip_bf16.h>

// SelfAttentionHead: B=4, S=4096, D=256, fp32 in/out.
// out = qp + softmax(tril_mul(qp kp^T / 16)) @ vp, masked entries enter softmax as 0.
// R4: m214-style attention: 32x32x16 MFMA, swapped QK^T (in-register softmax), KVBLK=32
// double-buffered LDS staged via global_load_lds (pre-swizzled source), 4-way split-K with
// bf16 partials; combine merges 4 partials + masked-zero correction + qp residual.

typedef __bf16 bf16x8 __attribute__((ext_vector_type(8)));
typedef float f32x4 __attribute__((ext_vector_type(4)));
typedef float f32x16 __attribute__((ext_vector_type(16)));
typedef unsigned int u32x4 __attribute__((ext_vector_type(4)));

#define MASKV -3.0e38f

__device__ __forceinline__ unsigned short f2bf_u(float f) {
  unsigned u = __float_as_uint(f);
  u += 0x7fffu + ((u >> 16) & 1u);
  return (unsigned short)(u >> 16);
}
__device__ __forceinline__ float bf2f(unsigned u16) {
  return __uint_as_float(u16 << 16);
}

// ---------------- WT[j][k] = bf16(W[k][j]) ----------------
__global__ __launch_bounds__(256) void wt_kernel(
    const float* __restrict__ Wq, const float* __restrict__ Wk, const float* __restrict__ Wv,
    unsigned short* __restrict__ WTq, unsigned short* __restrict__ WTk, unsigned short* __restrict__ WTv) {
  int j = blockIdx.x & 255;
  int wsel = blockIdx.x >> 8;
  const float* W = wsel == 0 ? Wq : (wsel == 1 ? Wk : Wv);
  unsigned short* WT = wsel == 0 ? WTq : (wsel == 1 ? WTk : WTv);
  int k = threadIdx.x;
  WT[j * 256 + k] = f2bf_u(W[k * 256 + j]);
}

// ---------------- Fused projection GEMMs: grid (256, 3) ----------------
__global__ __launch_bounds__(256) void proj_all_kernel(
    const float* __restrict__ q_in, const float* __restrict__ k_in, const float* __restrict__ v_in,
    const unsigned short* __restrict__ WTq, const unsigned short* __restrict__ WTk,
    const unsigned short* __restrict__ WTv,
    const float* __restrict__ bq, const float* __restrict__ bk, const float* __restrict__ bv,
    float* __restrict__ qpf, unsigned short* __restrict__ qpb,
    unsigned short* __restrict__ kpb,
    float* __restrict__ vpf, unsigned short* __restrict__ vptb) {
  int mode = blockIdx.y;
  const float* X = mode == 0 ? q_in : (mode == 1 ? k_in : v_in);
  const unsigned short* WT = mode == 0 ? WTq : (mode == 1 ? WTk : WTv);
  const float* bias = mode == 0 ? bq : (mode == 1 ? bk : bv);

  int rt = blockIdx.x;
  int tid = threadIdx.x;
  int w = tid >> 6, l = tid & 63, g = l >> 4, lm = l & 15;
  int arow = rt * 64 + w * 16 + lm;

  f32x4 acc[16];
#pragma unroll
  for (int i = 0; i < 16; i++) acc[i] = (f32x4){0.f, 0.f, 0.f, 0.f};

#pragma unroll
  for (int kb = 0; kb < 256; kb += 32) {
    const float* ap = X + arow * 256 + kb + 8 * g;
    float4 a0 = *(const float4*)ap;
    float4 a1 = *(const float4*)(ap + 4);
    bf16x8 af;
    af[0] = (__bf16)a0.x; af[1] = (__bf16)a0.y; af[2] = (__bf16)a0.z; af[3] = (__bf16)a0.w;
    af[4] = (__bf16)a1.x; af[5] = (__bf16)a1.y; af[6] = (__bf16)a1.z; af[7] = (__bf16)a1.w;
#pragma unroll
    for (int nt = 0; nt < 16; nt++) {
      bf16x8 bf = *(const bf16x8*)(WT + (nt * 16 + lm) * 256 + kb + 8 * g);
      acc[nt] = __builtin_amdgcn_mfma_f32_16x16x32_bf16(af, bf, acc[nt], 0, 0, 0);
    }
  }

#pragma unroll
  for (int nt = 0; nt < 16; nt++) {
    int col = nt * 16 + lm;
    float bb = bias[col];
#pragma unroll
    for (int r = 0; r < 4; r++) {
      int orow = rt * 64 + w * 16 + 4 * g + r;
      float v = acc[nt][r] + bb;
      int idx = orow * 256 + col;
      if (mode == 0) {
        qpf[idx] = v;
        qpb[idx] = f2bf_u(v * 0.0625f);  // fold 1/sqrt(D)=1/16 into Q
      } else if (mode == 1) {
        kpb[idx] = f2bf_u(v);
      } else {
        vpf[idx] = v;
        int b = orow >> 12, s = orow & 4095;
        vptb[(b * 256 + col) * 4096 + s] = f2bf_u(v);  // vpT[b][d][s]
      }
    }
  }
}

// ---------------- Suffix-sum of vp (exclusive), 64-row chunks ----------------
__global__ __launch_bounds__(256) void scan1(const float* __restrict__ vpf, float* __restrict__ ctot) {
  int c = blockIdx.x, b = blockIdx.y, d = threadIdx.x;
  const float* base = vpf + (b * 4096 + c * 64) * 256 + d;
  float acc = 0.f;
#pragma unroll 4
  for (int r = 0; r < 64; r++) acc += base[r * 256];
  ctot[(b * 64 + c) * 256 + d] = acc;
}

__global__ __launch_bounds__(256) void scan2(const float* __restrict__ vpf, const float* __restrict__ ctot,
                                             float* __restrict__ suffv) {
  int c = blockIdx.x, b = blockIdx.y, d = threadIdx.x;
  float acc = 0.f;
  for (int c2 = c + 1; c2 < 64; c2++) acc += ctot[(b * 64 + c2) * 256 + d];
  const float* base = vpf + (b * 4096 + c * 64) * 256 + d;
  float* sbase = suffv + (b * 4096 + c * 64) * 256 + d;
  for (int r = 63; r >= 0; r--) {
    sbase[r * 256] = acc;
    acc += base[r * 256];
  }
}

// ---------------- Flash attention, 32x32 MFMA, swapped QK^T ----------------
// 512 blocks x 256 threads (4 waves x 32 q-rows = 128 q-rows/block), 4-way split-K.
// bid&7: b=(bid&7)>>1 (batch pinned to XCD pair), slo=bid&1. k=bid>>3: k<32 -> big tiles
// (qb=31-(k>>1)) descending; k>=32 -> small ascending; s = (k&1)*2 + slo.
// LDS 64KB: K[2][32][256] + Vt[2][256][32], staged by global_load_lds w=16 with
// pre-swizzled global source (K chunk^=row&7, V chunk^=(d>>1)&3); reads use same XOR.
__global__ __launch_bounds__(256, 2) void attn4_kernel(
    const unsigned short* __restrict__ qpb, const unsigned short* __restrict__ kpb,
    const unsigned short* __restrict__ vptb,
    unsigned short* __restrict__ slot01,  // d_out as bf16 partials, row-interleaved [grow][s][256]
    unsigned short* __restrict__ slot23,  // vpf as bf16 partials, [s-2][grow][256]
    float* __restrict__ mzbuf) {
  extern __shared__ char smem[];

  int bid = blockIdx.x;
  int low = bid & 7;
  int b = low >> 1, slo = low & 1;
  int k = bid >> 3;
  int qb = (k < 32) ? (31 - (k >> 1)) : ((k - 32) >> 1);
  int s = (k & 1) * 2 + slo;

  int tid = threadIdx.x;
  int wv = tid >> 6, l = tid & 63;
  int hi = l >> 5, r32 = l & 31;
  int vsw = (r32 >> 1) & 3;       // V read swizzle (indep of dt)
  int ksw = r32 & 7;              // K read swizzle

  int qbase = qb * 128, qwave = qbase + 32 * wv;
  int qglob = qwave + r32;        // this lane's softmax q-row

  int t0 = s * (qb + 1), t1 = (s + 1) * (qb + 1);

  // Q as B-fragments (col = lane&31 = q-row, k-depth = d), pre-scaled by 1/16
  bf16x8 qf[16];
  const unsigned short* qsrc = qpb + (size_t)(b * 4096 + qwave + r32) * 256;
#pragma unroll
  for (int st = 0; st < 16; st++) qf[st] = *(const bf16x8*)(qsrc + st * 16 + 8 * hi);

  f32x16 O[8];
#pragma unroll
  for (int dt = 0; dt < 8; dt++)
#pragma unroll
    for (int e = 0; e < 16; e++) O[dt][e] = 0.f;
  float m_ = -1e30f, Z_ = 0.f;

  auto STAGE = [&](int bufIdx, int kt) {
    int kb2 = kt * 32;
    char* Kdst = smem + bufIdx * 16384;
    char* Vdst = smem + 32768 + bufIdx * 16384;
#pragma unroll
    for (int j2 = 0; j2 < 4; j2++) {
      int j = wv * 4 + j2;
      int row = j * 2 + (l >> 5);
      int cc = (l & 31) ^ (row & 7);
      const unsigned short* src = kpb + (size_t)(b * 4096 + kb2 + row) * 256 + cc * 8;
      __builtin_amdgcn_global_load_lds(
          (const __attribute__((address_space(1))) unsigned int*)src,
          (__attribute__((address_space(3))) unsigned int*)(Kdst + j * 1024), 16, 0, 0);
    }
#pragma unroll
    for (int j2 = 0; j2 < 4; j2++) {
      int j = wv * 4 + j2;
      int d = j * 16 + (l >> 2);
      int cc = (l & 3) ^ ((l >> 3) & 3);
      const unsigned short* src = vptb + (size_t)(b * 256 + d) * 4096 + kb2 + cc * 8;
      __builtin_amdgcn_global_load_lds(
          (const __attribute__((address_space(1))) unsigned int*)src,
          (__attribute__((address_space(3))) unsigned int*)(Vdst + j * 1024), 16, 0, 0);
    }
  };

  STAGE(0, t0);
  asm volatile("s_waitcnt vmcnt(0)" ::: "memory");
  __syncthreads();

  for (int kt = t0; kt < t1; kt++) {
    int cur = (kt - t0) & 1;
    if (kt + 1 < t1) STAGE(cur ^ 1, kt + 1);
    int kbase = kt * 32;

    if (kbase <= qwave + 31) {  // not fully masked for this wave
      const char* Kp = smem + cur * 16384;
      const char* Vp = smem + 32768 + cur * 16384;

      // ---- QK^T (swapped): St[key][q], A=K frag, B=Q frag ----
      f32x16 St;
#pragma unroll
      for (int e = 0; e < 16; e++) St[e] = 0.f;
#pragma unroll
      for (int st = 0; st < 16; st++) {
        bf16x8 kf = *(const bf16x8*)(Kp + r32 * 512 + (((2 * st + hi) ^ ksw) * 16));
        St = __builtin_amdgcn_mfma_f32_32x32x16_bf16(kf, qf[st], St, 0, 0, 0);
      }

      // ---- causal mask (zero-mask handled via combine correction) ----
      if (kbase + 31 > qglob) {
#pragma unroll
        for (int r = 0; r < 16; r++) {
          int kg = kbase + (r & 3) + 8 * (r >> 2) + 4 * hi;
          if (kg > qglob) St[r] = MASKV;
        }
      }

      // ---- in-register online softmax (row = this lane's q) ----
      float mx = St[0];
#pragma unroll
      for (int r = 1; r < 16; r++) mx = fmaxf(mx, St[r]);
      mx = fmaxf(mx, __shfl_xor(mx, 32));
      bool upd = __any(mx > m_ + 8.f);
      if (upd) {
        float mn = fmaxf(m_, mx);
        float scl = __expf(m_ - mn);
        m_ = mn;
        Z_ *= scl;
#pragma unroll
        for (int r = 0; r < 16; r++) {
          int qr = (r & 3) + 8 * (r >> 2) + 4 * hi;
          float sb = __uint_as_float(
              (unsigned)__builtin_amdgcn_ds_bpermute(qr * 4, (int)__float_as_uint(scl)));
#pragma unroll
          for (int dt = 0; dt < 8; dt++) O[dt][r] *= sb;
        }
      }
      float p[16];
      float rs = 0.f;
#pragma unroll
      for (int r = 0; r < 16; r++) {
        p[r] = __expf(St[r] - m_);
        rs += p[r];
      }
      rs += __shfl_xor(rs, 32);
      Z_ += rs;

      // ---- P -> bf16 A-fragments (T12 pack + cross-half exchange) ----
      unsigned X[8];
#pragma unroll
      for (int i = 0; i < 8; i++)
        X[i] = (unsigned)f2bf_u(p[2 * i]) | ((unsigned)f2bf_u(p[2 * i + 1]) << 16);
      unsigned Y0 = (unsigned)__shfl_xor((int)X[0], 32);
      unsigned Y1 = (unsigned)__shfl_xor((int)X[1], 32);
      unsigned Y2 = (unsigned)__shfl_xor((int)X[2], 32);
      unsigned Y3 = (unsigned)__shfl_xor((int)X[3], 32);
      unsigned Y4 = (unsigned)__shfl_xor((int)X[4], 32);
      unsigned Y5 = (unsigned)__shfl_xor((int)X[5], 32);
      unsigned Y6 = (unsigned)__shfl_xor((int)X[6], 32);
      unsigned Y7 = (unsigned)__shfl_xor((int)X[7], 32);
      u32x4 A0, A1;
      A0[0] = hi ? Y2 : X[0]; A0[1] = hi ? Y3 : X[1];
      A0[2] = hi ? X[2] : Y0; A0[3] = hi ? X[3] : Y1;
      A1[0] = hi ? Y6 : X[4]; A1[1] = hi ? Y7 : X[5];
      A1[2] = hi ? X[6] : Y4; A1[3] = hi ? X[7] : Y5;
      bf16x8 pa0 = __builtin_bit_cast(bf16x8, A0);
      bf16x8 pa1 = __builtin_bit_cast(bf16x8, A1);

      // ---- PV: O[q][d] += P @ V, B=V frag from LDS ----
#pragma unroll
      for (int dt = 0; dt < 8; dt++) {
        bf16x8 vf0 = *(const bf16x8*)(Vp + (dt * 32 + r32) * 64 + ((hi ^ vsw) * 16));
        O[dt] = __builtin_amdgcn_mfma_f32_32x32x16_bf16(pa0, vf0, O[dt], 0, 0, 0);
      }
#pragma unroll
      for (int dt = 0; dt < 8; dt++) {
        bf16x8 vf1 = *(const bf16x8*)(Vp + (dt * 32 + r32) * 64 + (((2 + hi) ^ vsw) * 16));
        O[dt] = __builtin_amdgcn_mfma_f32_32x32x16_bf16(pa1, vf1, O[dt], 0, 0, 0);
      }
    }

    asm volatile("s_waitcnt vmcnt(0)" ::: "memory");
    __syncthreads();
  }

  // ---- write partial stats + bf16 O ----
  int grow_base = b * 4096 + qwave;
  if (hi == 0) {
    mzbuf[s * 16384 + grow_base + r32] = m_;
    mzbuf[65536 + s * 16384 + grow_base + r32] = Z_;
  }
#pragma unroll
  for (int r = 0; r < 16; r++) {
    int qr = (r & 3) + 8 * (r >> 2) + 4 * hi;
    size_t grow = (size_t)(grow_base + qr);
#pragma unroll
    for (int dt = 0; dt < 8; dt++) {
      int dcol = dt * 32 + r32;
      unsigned short vb = f2bf_u(O[dt][r]);
      if (s < 2)
        slot01[grow * 512 + (size_t)s * 256 + dcol] = vb;
      else
        slot23[(size_t)(s - 2) * 4194304 + grow * 256 + dcol] = vb;
    }
  }
}

// ---------------- combine: merge 4 partials + masked-zero correction + qp add ----------------
__global__ __launch_bounds__(256) void combine4_kernel(
    const float* __restrict__ mzbuf, const unsigned short* __restrict__ slot23,
    const float* __restrict__ qpf, const float* __restrict__ suffv, float* __restrict__ out) {
  int grow = blockIdx.x * 4 + (threadIdx.x >> 6);
  int col = (threadIdx.x & 63) * 4;
  const unsigned short* slot01 = (const unsigned short*)out;

  float m0 = mzbuf[grow], m1 = mzbuf[16384 + grow];
  float m2 = mzbuf[32768 + grow], m3 = mzbuf[49152 + grow];
  float Z0 = mzbuf[65536 + grow], Z1 = mzbuf[65536 + 16384 + grow];
  float Z2 = mzbuf[65536 + 32768 + grow], Z3 = mzbuf[65536 + 49152 + grow];
  float M = fmaxf(fmaxf(m0, m1), fmaxf(m2, m3));
  float f0 = __expf(m0 - M), f1 = __expf(m1 - M), f2 = __expf(m2 - M), f3 = __expf(m3 - M);
  float Zm = Z0 * f0 + Z1 * f1 + Z2 * f2 + Z3 * f3;

  int q = grow & 4095;
  int nmask = 4095 - q;
  float scl, e0, Zf;
  if (nmask > 0) {
    float Mf = fmaxf(M, 0.f);
    scl = __expf(M - Mf);
    e0 = __expf(-Mf);
    Zf = Zm * scl + (float)nmask * e0;
  } else {
    scl = 1.f; e0 = 0.f; Zf = Zm;
  }
  float rZ = 1.f / Zf;
  float a0 = f0 * scl * rZ, a1 = f1 * scl * rZ, a2 = f2 * scl * rZ, a3 = f3 * scl * rZ;
  float asv = e0 * rZ;

  uint2 s0 = *(const uint2*)(slot01 + (size_t)grow * 512 + col);
  uint2 s1 = *(const uint2*)(slot01 + (size_t)grow * 512 + 256 + col);
  uint2 s2 = *(const uint2*)(slot23 + (size_t)grow * 256 + col);
  uint2 s3 = *(const uint2*)(slot23 + 4194304 + (size_t)grow * 256 + col);
  size_t base = (size_t)grow * 256 + col;
  float4 qp = *(const float4*)&qpf[base];
  float4 sv = *(const float4*)&suffv[base];

  __syncthreads();  // all slot01 (= out bytes) reads in this block complete before writes

  float4 res;
  res.x = qp.x + sv.x * asv + bf2f(s0.x & 0xffff) * a0 + bf2f(s1.x & 0xffff) * a1 +
          bf2f(s2.x & 0xffff) * a2 + bf2f(s3.x & 0xffff) * a3;
  res.y = qp.y + sv.y * asv + bf2f(s0.x >> 16) * a0 + bf2f(s1.x >> 16) * a1 +
          bf2f(s2.x >> 16) * a2 + bf2f(s3.x >> 16) * a3;
  res.z = qp.z + sv.z * asv + bf2f(s0.y & 0xffff) * a0 + bf2f(s1.y & 0xffff) * a1 +
          bf2f(s2.y & 0xffff) * a2 + bf2f(s3.y & 0xffff) * a3;
  res.w = qp.w + sv.w * asv + bf2f(s0.y >> 16) * a0 + bf2f(s1.y >> 16) * a1 +
          bf2f(s2.y >> 16) * a2 + bf2f(s3.y >> 16) * a3;
  *(float4*)&out[base] = res;
}

// ---------------- launch ----------------
extern "C" void kernel_launch(void* const* d_in, const int* in_sizes, int n_in,
                              void* d_out, int out_size, void* d_ws, size_t ws_size,
                              hipStream_t stream) {
  const float* v_in = (const float*)d_in[0];
  const float* k_in = (const float*)d_in[1];
  const float* q_in = (const float*)d_in[2];
  const float* Wq = (const float*)d_in[3];
  const float* bq = (const float*)d_in[4];
  const float* Wk = (const float*)d_in[5];
  const float* bk = (const float*)d_in[6];
  const float* Wv = (const float*)d_in[7];
  const float* bv = (const float*)d_in[8];
  float* out = (float*)d_out;

  char* p = (char*)d_ws;
  float* qpf = (float*)(p + 0);                            // 16 MB
  float* vpf = (float*)(p + 16777216);                     // 16 MB (scans); then bf16 slots 2,3
  float* suffv = (float*)(p + 33554432);                   // 16 MB
  unsigned short* qpb = (unsigned short*)(p + 50331648);   // 8 MB (scaled 1/16)
  unsigned short* kpb = (unsigned short*)(p + 58720256);   // 8 MB
  unsigned short* vptb = (unsigned short*)(p + 67108864);  // 8 MB, [B][D][S]
  unsigned short* WTq = (unsigned short*)(p + 75497472);   // 128 KB (proj phase only)
  unsigned short* WTk = (unsigned short*)(p + 75628544);   // 128 KB
  unsigned short* WTv = (unsigned short*)(p + 75759616);   // 128 KB
  float* ctot = (float*)(p + 75759616);                    // 256 KB (scan phase, after WTv dead)
  float* mzbuf = (float*)(p + 75497472);                   // 512 KB (attn phase, WT/ctot dead)
  unsigned short* slot01 = (unsigned short*)d_out;         // bf16 partials s=0,1 (row-interleaved)
  unsigned short* slot23 = (unsigned short*)vpf;           // bf16 partials s=2,3

  hipFuncSetAttribute((const void*)attn4_kernel,
                      hipFuncAttributeMaxDynamicSharedMemorySize, 65536);

  wt_kernel<<<768, 256, 0, stream>>>(Wq, Wk, Wv, WTq, WTk, WTv);
  proj_all_kernel<<<dim3(256, 3), 256, 0, stream>>>(q_in, k_in, v_in, WTq, WTk, WTv,
                                                    bq, bk, bv, qpf, qpb, kpb, vpf, vptb);
  scan1<<<dim3(64, 4), 256, 0, stream>>>(vpf, ctot);
  scan2<<<dim3(64, 4), 256, 0, stream>>>(vpf, ctot, suffv);
  attn4_kernel<<<512, 256, 65536, stream>>>(qpb, kpb, vptb, slot01, slot23, mzbuf);
  combine4_kernel<<<4096, 256, 0, stream>>>(mzbuf, slot23, qpf, suffv, out);
}